// Round 11
// baseline (43.185 us; speedup 1.0000x reference)
//
#include <hip/hip_runtime.h>

#define ROWS 64      // rows per slab
#define NSLAB 2      // slabs per block
#define TPB  192     // 3 waves: wave k owns matrix column k
#define XDIM 99
#define NJ   26
#define OUTW 78      // output floats per row
#define SLABF (ROWS * XDIM)   // 6336 floats per slab

// LDS-only barrier: waits ds ops, NOT outstanding global loads (keeps prefetch
// + stores in flight across phase boundaries). All memory ops ordered by the
// "memory" clobber; no non-memory consumers of LDS data exist here (rule #18 n/a).
#define LGKM_BAR() asm volatile("s_waitcnt lgkmcnt(0)\n\ts_barrier" ::: "memory")

__device__ __forceinline__ float fast_rcp(float a)  { return __builtin_amdgcn_rcpf(a); }
__device__ __forceinline__ float fast_sqrt(float a) { return __builtin_amdgcn_sqrtf(a); }

__device__ __forceinline__ void rodrigues(float ax, float ay, float az, float* R) {
    const float EPS = 1.1920928955078125e-07f;   // np.finfo(np.float32).eps
    float t = fast_sqrt(ax*ax + ay*ay + az*az);
    float inv = fast_rcp(t + EPS);
    float r0 = ax*inv, r1 = ay*inv, r2 = az*inv;
    float s, c;
    __sincosf(t, &s, &c);                        // shared range reduction
    float omc = 1.0f - c;
    float r00 = r0*r0, r11 = r1*r1, r22 = r2*r2;
    float r01 = r0*r1, r02 = r0*r2, r12 = r1*r2;
    R[0] = 1.0f - omc*(r11 + r22);
    R[1] = -s*r2 + omc*r01;
    R[2] =  s*r1 + omc*r02;
    R[3] =  s*r2 + omc*r01;
    R[4] = 1.0f - omc*(r00 + r22);
    R[5] = -s*r0 + omc*r12;
    R[6] = -s*r1 + omc*r02;
    R[7] =  s*r0 + omc*r12;
    R[8] = 1.0f - omc*(r00 + r11);
}

__global__ __launch_bounds__(TPB, 4) void skel_fk(const float* __restrict__ x,
                                                  const float* __restrict__ off,
                                                  float* __restrict__ out) {
    __shared__ float buf[NSLAB][SLABF];          // 2 x 25344 B = 50688 B -> 3 blocks/CU
    const int t = threadIdx.x;
    const int w = t >> 6;                        // wave id 0..2 (uniform)
    const int l = t & 63;                        // lane
    const int row0 = blockIdx.x * (ROWS * NSLAB);

    // ---- prefetch BOTH slabs via global_load_lds (one vmcnt drain for all) ----
    #pragma unroll
    for (int sl = 0; sl < NSLAB; ++sl) {
        const float* gs = x + (long long)(row0 + sl * ROWS) * XDIM;
        const float* gw = gs + w * 2112 + l * 4;     // lane's 16B in wave slab-third
        float* lw = &buf[sl][0] + w * 2112;          // wave-uniform LDS base
        #pragma unroll
        for (int j = 0; j < 8; ++j) {
            __builtin_amdgcn_global_load_lds(
                (const __attribute__((address_space(1))) unsigned int*)(gw + j * 256),
                (__attribute__((address_space(3))) unsigned int*)(lw + j * 256),
                16, 0, 0);
        }
        __builtin_amdgcn_global_load_lds(
            (const __attribute__((address_space(1))) unsigned int*)(gs + w * 2112 + 2048 + l),
            (__attribute__((address_space(3))) unsigned int*)(&buf[sl][0] + w * 2112 + 2048),
            4, 0, 0);
    }
    __syncthreads();                             // ONE full vmcnt(0) drain: both resident

    // slot tables (slot 0 = hip, slots 1..25 follow ORDER)
    constexpr int OFF_IDX[NJ] = {0,1,2,3,4,6,7,8,9,11,12,13,14,15,16,17,18,19,20,22,24,25,26,27,28,30};
    constexpr int PAR[NJ]     = {-1,0,1,2,3,0,5,6,7,0,9,10,11,12,10,14,15,16,17,17,10,20,21,22,23,23};

    const int k = w;                             // matrix column (wave-uniform)

    #pragma unroll
    for (int sl = 0; sl < NSLAB; ++sl) {
        float* wrow = &buf[sl][l * XDIM];
        const float* row = wrow;

        float ac[NJ][3];
        float pp[NJ];
        {
            float R[9];
            rodrigues(row[3], row[4], row[5], R);
            ac[0][0] = (k == 0) ? R[0] : ((k == 1) ? R[1] : R[2]);
            ac[0][1] = (k == 0) ? R[3] : ((k == 1) ? R[4] : R[5]);
            ac[0][2] = (k == 0) ? R[6] : ((k == 1) ? R[7] : R[8]);
            pp[0] = off[k] + row[k];
        }

        #pragma unroll
        for (int s = 1; s < NJ; ++s) {
            const int i  = OFF_IDX[s];
            const int pa = PAR[s];
            float L[9];
            rodrigues(row[3*i+3], row[3*i+4], row[3*i+5], L);
            const float o0 = off[3*i], o1 = off[3*i+1], o2 = off[3*i+2];
            pp[s] = o0*ac[pa][0] + o1*ac[pa][1] + o2*ac[pa][2] + pp[pa];
            ac[s][0] = L[0]*ac[pa][0] + L[1]*ac[pa][1] + L[2]*ac[pa][2];
            ac[s][1] = L[3]*ac[pa][0] + L[4]*ac[pa][1] + L[5]*ac[pa][2];
            ac[s][2] = L[6]*ac[pa][0] + L[7]*ac[pa][1] + L[8]*ac[pa][2];
        }

        LGKM_BAR();                              // all slab-sl reads done in every wave

        // ---- pos transpose into (dead) input region of slab sl ----
        #pragma unroll
        for (int s = 0; s < NJ; ++s)
            wrow[3*s + k] = pp[s];               // banks (3l+3s+k)%32 -> 2-way, free

        LGKM_BAR();                              // transpose visible to all waves

        // ---- coalesced flush: full 64B lines, single touch; stores fire-and-forget ----
        {
            float* oblk = out + (long long)(row0 + sl * ROWS) * OUTW;
            #pragma unroll
            for (int j = 0; j < 26; ++j) {       // 192*26 = 4992 = 64*78 exact
                int m = t + j * TPB;
                int rr = m / OUTW;               // const divisor -> magic mul
                int cc = m - rr * OUTW;
                oblk[m] = buf[sl][rr * XDIM + cc];
            }
        }
        // no barrier needed between flush(sl) and compute(sl+1): disjoint buffers
    }
}

extern "C" void kernel_launch(void* const* d_in, const int* in_sizes, int n_in,
                              void* d_out, int out_size, void* d_ws, size_t ws_size,
                              hipStream_t stream) {
    const float* x   = (const float*)d_in[0];
    const float* off = (const float*)d_in[1];
    float* out = (float*)d_out;
    const int B = in_sizes[0] / XDIM;            // 262144
    const int grid = B / (ROWS * NSLAB);         // 2048 exact
    skel_fk<<<grid, TPB, 0, stream>>>(x, off, out);
}

// Round 12
// 41.260 us; speedup vs baseline: 1.0467x; 1.0467x over previous
//
#include <hip/hip_runtime.h>

#define ROWS 64      // rows per block
#define TPB  192     // 3 waves: wave k owns matrix column k for all 64 rows
#define XDIM 99
#define NJ   26
#define OUTW 78      // output floats per row

// ~1-2 ULP primitives; output threshold is 0.309 ABSOLUTE (measured slack 5x) -> safe
__device__ __forceinline__ float fast_rcp(float a)  { return __builtin_amdgcn_rcpf(a); }
__device__ __forceinline__ float fast_sqrt(float a) { return __builtin_amdgcn_sqrtf(a); }

__device__ __forceinline__ void rodrigues(float ax, float ay, float az, float* R) {
    const float EPS = 1.1920928955078125e-07f;   // np.finfo(np.float32).eps
    float t = fast_sqrt(ax*ax + ay*ay + az*az);
    float inv = fast_rcp(t + EPS);
    float r0 = ax*inv, r1 = ay*inv, r2 = az*inv;
    float s, c;
    __sincosf(t, &s, &c);                        // shared range reduction
    float omc = 1.0f - c;
    float r00 = r0*r0, r11 = r1*r1, r22 = r2*r2;
    float r01 = r0*r1, r02 = r0*r2, r12 = r1*r2;
    R[0] = 1.0f - omc*(r11 + r22);
    R[1] = -s*r2 + omc*r01;
    R[2] =  s*r1 + omc*r02;
    R[3] =  s*r2 + omc*r01;
    R[4] = 1.0f - omc*(r00 + r22);
    R[5] = -s*r0 + omc*r12;
    R[6] = -s*r1 + omc*r02;
    R[7] =  s*r0 + omc*r12;
    R[8] = 1.0f - omc*(r00 + r11);
}

// launch_bounds (192,5): VGPR budget ~102 so the scheduler can hoist LDS reads;
// occupancy stays LDS-capped (25.3KB -> 6 blocks/CU = 18 waves = 4.5/SIMD).
__global__ __launch_bounds__(TPB, 5) void skel_fk(const float* __restrict__ x,
                                                  const float* __restrict__ off,
                                                  float* __restrict__ out) {
    __shared__ float buf[ROWS * XDIM];           // 25344 B = 3 waves x 8448 B slabs
    const int t = threadIdx.x;
    const int w = t >> 6;                        // wave id 0..2 (uniform per wave)
    const int l = t & 63;                        // lane
    const int row0 = blockIdx.x * ROWS;

    // ---- stage via global_load_lds: wave w DMAs bytes [w*8448, w*8448+8448) ----
    {
        const float* gsrc = x + (long long)row0 * XDIM;  // block slab base
        const float* gw = gsrc + w * 2112 + l * 4;       // lane's 16B within wave slab
        float* lw = buf + w * 2112;                      // wave-uniform LDS base
        #pragma unroll
        for (int j = 0; j < 8; ++j) {
            __builtin_amdgcn_global_load_lds(
                (const __attribute__((address_space(1))) unsigned int*)(gw + j * 256),
                (__attribute__((address_space(3))) unsigned int*)(lw + j * 256),
                16, 0, 0);
        }
        __builtin_amdgcn_global_load_lds(
            (const __attribute__((address_space(1))) unsigned int*)(gsrc + w * 2112 + 2048 + l),
            (__attribute__((address_space(3))) unsigned int*)(buf + w * 2112 + 2048),
            4, 0, 0);
    }
    __syncthreads();                             // one vmcnt(0) drain, slab resident

    const int r = l;                             // compute: lane = row, wave = column
    const int k = w;
    float* wrow = &buf[r * XDIM];
    const float* row = wrow;

    // slot tables (slot 0 = hip, slots 1..25 follow ORDER)
    constexpr int OFF_IDX[NJ] = {0,1,2,3,4,6,7,8,9,11,12,13,14,15,16,17,18,19,20,22,24,25,26,27,28,30};
    constexpr int PAR[NJ]     = {-1,0,1,2,3,0,5,6,7,0,9,10,11,12,10,14,15,16,17,17,10,20,21,22,23,23};

    float ac[NJ][3];   // column k of ang[slot]; compile-time indices -> registers
    float pp[NJ];      // component k of pos[slot]; kept in registers until flush

    {
        float R[9];
        rodrigues(row[3], row[4], row[5], R);
        ac[0][0] = (k == 0) ? R[0] : ((k == 1) ? R[1] : R[2]);
        ac[0][1] = (k == 0) ? R[3] : ((k == 1) ? R[4] : R[5]);
        ac[0][2] = (k == 0) ? R[6] : ((k == 1) ? R[7] : R[8]);
        pp[0] = off[k] + row[k];
    }

    // 2-deep triplet prefetch: slot s+2's LDS reads issue ~2 chain-steps early.
    // Parity-indexed double buffer; fully unrolled -> all indices compile-time.
    float pax = row[3*OFF_IDX[1]+3], pay = row[3*OFF_IDX[1]+4], paz = row[3*OFF_IDX[1]+5];
    float pbx = row[3*OFF_IDX[2]+3], pby = row[3*OFF_IDX[2]+4], pbz = row[3*OFF_IDX[2]+5];

    #pragma unroll
    for (int s = 1; s < NJ; ++s) {
        const int i  = OFF_IDX[s];
        const int pa = PAR[s];
        const float ax = (s & 1) ? pax : pbx;
        const float ay = (s & 1) ? pay : pby;
        const float az = (s & 1) ? paz : pbz;
        if (s + 2 < NJ) {                        // refill the buffer just consumed
            const int cn = 3*OFF_IDX[s+2] + 3;
            if (s & 1) { pax = row[cn]; pay = row[cn+1]; paz = row[cn+2]; }
            else       { pbx = row[cn]; pby = row[cn+1]; pbz = row[cn+2]; }
        }
        float L[9];
        rodrigues(ax, ay, az, L);                // redundant across 3 waves
        const float o0 = off[3*i], o1 = off[3*i+1], o2 = off[3*i+2];  // uniform
        pp[s] = o0*ac[pa][0] + o1*ac[pa][1] + o2*ac[pa][2] + pp[pa];
        ac[s][0] = L[0]*ac[pa][0] + L[1]*ac[pa][1] + L[2]*ac[pa][2];
        ac[s][1] = L[3]*ac[pa][0] + L[4]*ac[pa][1] + L[5]*ac[pa][2];
        ac[s][2] = L[6]*ac[pa][0] + L[7]*ac[pa][1] + L[8]*ac[pa][2];
    }

    __syncthreads();                             // all buf reads done in every wave

    // ---- pos transpose into (dead) input region: banks (3r+3s+k)%32 -> 2-way, free ----
    #pragma unroll
    for (int s = 0; s < NJ; ++s)
        wrow[3*s + k] = pp[s];                   // wrow = &buf[r*XDIM], r = lane
    __syncthreads();

    // ---- coalesced flush: consecutive lanes -> consecutive global dwords,
    //      full 64B lines, each line written exactly once ----
    {
        float* oblk = out + (long long)row0 * OUTW;
        #pragma unroll
        for (int j = 0; j < 26; ++j) {           // 192*26 = 4992 = 64*78 exact
            int m = t + j * TPB;
            int rr = m / OUTW;                   // const divisor -> magic mul
            int cc = m - rr * OUTW;
            oblk[m] = buf[rr * XDIM + cc];
        }
    }
}

extern "C" void kernel_launch(void* const* d_in, const int* in_sizes, int n_in,
                              void* d_out, int out_size, void* d_ws, size_t ws_size,
                              hipStream_t stream) {
    const float* x   = (const float*)d_in[0];
    const float* off = (const float*)d_in[1];
    float* out = (float*)d_out;
    const int B = in_sizes[0] / XDIM;      // 262144
    const int grid = B / ROWS;             // 4096
    skel_fk<<<grid, TPB, 0, stream>>>(x, off, out);
}

// Round 13
// 40.807 us; speedup vs baseline: 1.0583x; 1.0111x over previous
//
#include <hip/hip_runtime.h>

#define RPB  64      // rows per block = 1 per lane
#define TPB  64      // one wave
#define XDIM 99
#define NJ   26
#define OUTW 78
#define CH   32      // rows per output-transpose chunk

__device__ __forceinline__ float fast_rcp(float a)  { return __builtin_amdgcn_rcpf(a); }
__device__ __forceinline__ float fast_sqrt(float a) { return __builtin_amdgcn_sqrtf(a); }

__device__ __forceinline__ void rodrigues(float ax, float ay, float az, float* R) {
    const float EPS = 1.1920928955078125e-07f;   // np.finfo(np.float32).eps
    float t = fast_sqrt(ax*ax + ay*ay + az*az);
    float inv = fast_rcp(t + EPS);
    float r0 = ax*inv, r1 = ay*inv, r2 = az*inv;
    float s, c;
    __sincosf(t, &s, &c);
    float omc = 1.0f - c;
    float r00 = r0*r0, r11 = r1*r1, r22 = r2*r2;
    float r01 = r0*r1, r02 = r0*r2, r12 = r1*r2;
    R[0] = 1.0f - omc*(r11 + r22);
    R[1] = -s*r2 + omc*r01;
    R[2] =  s*r1 + omc*r02;
    R[3] =  s*r2 + omc*r01;
    R[4] = 1.0f - omc*(r00 + r22);
    R[5] = -s*r0 + omc*r12;
    R[6] = -s*r1 + omc*r02;
    R[7] =  s*r0 + omc*r12;
    R[8] = 1.0f - omc*(r00 + r11);
}

// (64,3): VGPR budget ~170 for the ang/pp live set; 12 waves/CU target.
__global__ __launch_bounds__(TPB, 3) void skel_fk(const float* __restrict__ x,
                                                  const float* __restrict__ off,
                                                  float* __restrict__ out) {
    __shared__ float tb[CH * OUTW];              // 9984 B, output transpose only
    const int l = threadIdx.x;
    const int row0 = blockIdx.x * RPB;
    // lane-owned row: sequential 26-triplet walk; ~4 touches/64B line, L1-resident
    const float* rp = x + (long long)(row0 + l) * XDIM;

    // slot tables (slot 0 = hip, slots 1..25 follow ORDER)
    constexpr int OFF_IDX[NJ] = {0,1,2,3,4,6,7,8,9,11,12,13,14,15,16,17,18,19,20,22,24,25,26,27,28,30};
    constexpr int PAR[NJ]     = {-1,0,1,2,3,0,5,6,7,0,9,10,11,12,10,14,15,16,17,17,10,20,21,22,23,23};

    float ang[NJ][9];   // compile-time indices -> SSA registers; dead matrices get killed
    float pp[NJ][3];    // full position vectors, live until flush

    {
        float R[9];
        rodrigues(rp[3], rp[4], rp[5], R);
        #pragma unroll
        for (int q = 0; q < 9; ++q) ang[0][q] = R[q];
        pp[0][0] = off[0] + rp[0];
        pp[0][1] = off[1] + rp[1];
        pp[0][2] = off[2] + rp[2];
    }

    #pragma unroll
    for (int s = 1; s < NJ; ++s) {
        const int i  = OFF_IDX[s];
        const int pa = PAR[s];
        float L[9];
        rodrigues(rp[3*i+3], rp[3*i+4], rp[3*i+5], L);   // direct gather, no LDS
        const float o0 = off[3*i], o1 = off[3*i+1], o2 = off[3*i+2];  // uniform
        #pragma unroll
        for (int c = 0; c < 3; ++c)
            pp[s][c] = o0*ang[pa][c] + o1*ang[pa][3+c] + o2*ang[pa][6+c] + pp[pa][c];
        #pragma unroll
        for (int j = 0; j < 3; ++j)
            #pragma unroll
            for (int kk = 0; kk < 3; ++kk)
                ang[s][3*j+kk] = L[3*j+0]*ang[pa][0+kk]
                               + L[3*j+1]*ang[pa][3+kk]
                               + L[3*j+2]*ang[pa][6+kk];
    }

    // ---- output: two 32-row chunks through LDS transpose; every global line
    //      full, aligned, written exactly once. Barriers are wave-local. ----
    #pragma unroll
    for (int c = 0; c < 2; ++c) {
        if (c) __syncthreads();                  // chunk-0 reads done
        if ((l >> 5) == c) {
            float* srow = &tb[(l & 31) * OUTW];  // 312B stride: b64 banks 2-way, free
            #pragma unroll
            for (int j = 0; j < 39; ++j) {       // 78 floats as 39 float2
                float2 v;
                v.x = pp[(2*j)   / 3][(2*j)   % 3];   // compile-time indices
                v.y = pp[(2*j+1) / 3][(2*j+1) % 3];
                *reinterpret_cast<float2*>(&srow[2*j]) = v;
            }
        }
        __syncthreads();
        float* ob = out + ((long long)row0 + CH * c) * OUTW;
        #pragma unroll
        for (int j = 0; j < 20; ++j) {           // 1248 float2 = 32 rows x 78
            int m = l + j * TPB;
            if (m < CH * OUTW / 2) {
                float2 v = *reinterpret_cast<const float2*>(&tb[2*m]);
                *reinterpret_cast<float2*>(&ob[2*m]) = v;
            }
        }
    }
}

extern "C" void kernel_launch(void* const* d_in, const int* in_sizes, int n_in,
                              void* d_out, int out_size, void* d_ws, size_t ws_size,
                              hipStream_t stream) {
    const float* x   = (const float*)d_in[0];
    const float* off = (const float*)d_in[1];
    float* out = (float*)d_out;
    const int B = in_sizes[0] / XDIM;      // 262144
    const int grid = B / RPB;              // 4096
    skel_fk<<<grid, TPB, 0, stream>>>(x, off, out);
}